// Round 8
// baseline (179.711 us; speedup 1.0000x reference)
//
#include <hip/hip_runtime.h>
#include <cstdint>
#include <cstddef>

#define S_LEN 4096
#define HID   512
#define NHEAD 8
#define HD    64
// (1/sqrt(64)) * log2(e)
#define SCALE_LOG2E 0.1803368801111204f

typedef __bf16 bf16;
typedef __bf16 bf16x8 __attribute__((ext_vector_type(8)));
typedef __bf16 bf16x4 __attribute__((ext_vector_type(4)));
typedef float  f32x4  __attribute__((ext_vector_type(4)));
typedef unsigned uint4v __attribute__((ext_vector_type(4)));

// ---------------- fused input conversion: X + 4 weights -> bf16 ----------------
// R15: folding this into GEMM staging regressed (+6.6us). Keep the kernel.
__global__ __launch_bounds__(256) void cvt_in(
    const float* __restrict__ hs, const float* __restrict__ wq,
    const float* __restrict__ wk, const float* __restrict__ wv,
    const float* __restrict__ wo,
    bf16* __restrict__ xb, bf16* __restrict__ wqb, bf16* __restrict__ wkb,
    bf16* __restrict__ wvb, bf16* __restrict__ wob)
{
    int e = (blockIdx.x * 256 + threadIdx.x) * 4;
    const float* s; bf16* d; int o;
    if (e < 2 * 1024 * 1024) { s = hs; d = xb; o = e; }
    else {
        int t = e - 2 * 1024 * 1024;
        int wi = t >> 18;
        o = t & ((1 << 18) - 1);
        s = (wi == 0) ? wq : (wi == 1) ? wk : (wi == 2) ? wv : wo;
        d = (wi == 0) ? wqb : (wi == 1) ? wkb : (wi == 2) ? wvb : wob;
    }
    const float4 v = *(const float4*)(s + o);
    bf16x4 ob;
    ob[0] = (bf16)v.x; ob[1] = (bf16)v.y; ob[2] = (bf16)v.z; ob[3] = (bf16)v.w;
    *(bf16x4*)(d + o) = ob;
}

// ---------------- QKV GEMM, bf16 in, fused RoPE/transpose epilogue ----------------
__global__ __launch_bounds__(256) void gemm_qkv(
    const bf16* __restrict__ Xb,
    const bf16* __restrict__ W0, const bf16* __restrict__ W1, const bf16* __restrict__ W2,
    const float* __restrict__ cosT, const float* __restrict__ sinT,
    const int* __restrict__ nregp,
    bf16* __restrict__ Qh, bf16* __restrict__ Kh, bf16* __restrict__ Vt)
{
    const int z = blockIdx.z;
    const bf16* W = (z == 0) ? W0 : (z == 1 ? W1 : W2);
    const int m0 = blockIdx.y * 64, n0 = blockIdx.x * 128;
    __shared__ bf16 lA[64][8][8];
    __shared__ bf16 lB[128][8][8];
    __shared__ bf16 scratch[64][136];
    const int tid = threadIdx.x;
    const int lane = tid & 63, w = tid >> 6;
    const int l16 = lane & 15, lc = lane >> 4, l7 = lane & 7;
    const int wm = (w & 1) * 32, wn = (w >> 1) * 64;
    f32x4 acc[2][4] = {};

    for (int k0 = 0; k0 < HID; k0 += 64) {
        __syncthreads();
#pragma unroll
        for (int i = 0; i < 2; i++) {
            int uu = tid + 256 * i;
            int m = uu >> 3, c = uu & 7;
            *(bf16x8*)(&lA[m][c ^ (m & 7)][0]) =
                *(const bf16x8*)(Xb + (size_t)(m0 + m) * HID + k0 + 8 * c);
        }
#pragma unroll
        for (int i = 0; i < 4; i++) {
            int uu = tid + 256 * i;
            int m = uu >> 3, c = uu & 7;
            *(bf16x8*)(&lB[m][c ^ (m & 7)][0]) =
                *(const bf16x8*)(W + (size_t)(n0 + m) * HID + k0 + 8 * c);
        }
        __syncthreads();
#pragma unroll
        for (int ks = 0; ks < 2; ks++) {
            bf16x8 af[2], bfr[4];
#pragma unroll
            for (int i = 0; i < 2; i++)
                af[i]  = *(const bf16x8*)(&lA[wm + 16 * i + l16][(4 * ks + lc) ^ l7][0]);
#pragma unroll
            for (int j = 0; j < 4; j++)
                bfr[j] = *(const bf16x8*)(&lB[wn + 16 * j + l16][(4 * ks + lc) ^ l7][0]);
#pragma unroll
            for (int i = 0; i < 2; i++)
#pragma unroll
                for (int j = 0; j < 4; j++)
                    acc[i][j] = __builtin_amdgcn_mfma_f32_16x16x32_bf16(
                        af[i], bfr[j], acc[i][j], 0, 0, 0);
        }
    }

    if (z == 2) {
        const int h = (n0 + wn) >> 6;
#pragma unroll
        for (int i = 0; i < 2; i++) {
            const int s0r = m0 + wm + 16 * i + 4 * lc;
#pragma unroll
            for (int j = 0; j < 4; j++) {
                const int dl = 16 * j + l16;
                bf16x4 o;
#pragma unroll
                for (int r = 0; r < 4; r++) o[r] = (bf16)acc[i][j][r];
                *(bf16x4*)(Vt + ((size_t)(h * HD + dl)) * S_LEN + s0r) = o;
            }
        }
    } else {
        const int nreg = *nregp;
        bf16* dst = (z == 0) ? Qh : Kh;
#pragma unroll
        for (int i = 0; i < 2; i++) {
            const int sl0 = wm + 16 * i + 4 * lc;
#pragma unroll
            for (int r = 0; r < 4; r++) {
                const int s = m0 + sl0 + r;
                float c0 = 1.f, sn0 = 0.f, c1 = 1.f, sn1 = 0.f;
                if (s >= nreg) {
                    const int p = s - nreg;
                    c0  = cosT[(size_t)p * HD + l16];
                    sn0 = sinT[(size_t)p * HD + l16];
                    c1  = cosT[(size_t)p * HD + 16 + l16];
                    sn1 = sinT[(size_t)p * HD + 16 + l16];
                }
                const float x0 = acc[i][0][r], x1 = acc[i][1][r];
                const float x2 = acc[i][2][r], x3 = acc[i][3][r];
                bf16* row = &scratch[sl0 + r][wn];
                row[l16]      = (bf16)(x0 * c0 - x2 * sn0);
                row[l16 + 16] = (bf16)(x1 * c1 - x3 * sn1);
                row[l16 + 32] = (bf16)(x2 * c0 + x0 * sn0);
                row[l16 + 48] = (bf16)(x3 * c1 + x1 * sn1);
            }
        }
        __syncthreads();
        const int h0 = n0 >> 6;
#pragma unroll
        for (int i = 0; i < 4; i++) {
            int u = tid + 256 * i;
            int row = u >> 4, c = u & 15;
            bf16x8 val = *(const bf16x8*)(&scratch[row][c * 8]);
            *(bf16x8*)(dst + ((size_t)(h0 + (c >> 3)) * S_LEN + m0 + row) * HD +
                       (c & 7) * 8) = val;
        }
    }
}

// ---------------- output GEMM: bf16 A x bf16 W, fp32 out ----------
__global__ __launch_bounds__(256) void gemm_out(
    const bf16* __restrict__ X, const bf16* __restrict__ Wb,
    float* __restrict__ Y)
{
    const int m0 = blockIdx.y * 64, n0 = blockIdx.x * 64;
    __shared__ bf16 lA[64][8][8];
    __shared__ bf16 lB[64][8][8];
    const int tid = threadIdx.x;
    const int lane = tid & 63, w = tid >> 6;
    const int l16 = lane & 15, lc = lane >> 4, l7 = lane & 7;
    const int wm = (w & 1) * 32, wn = (w >> 1) * 32;
    f32x4 acc[2][2] = {};

    for (int k0 = 0; k0 < HID; k0 += 64) {
        __syncthreads();
#pragma unroll
        for (int i = 0; i < 2; i++) {
            int uu = tid + 256 * i;
            int m = uu >> 3, c = uu & 7;
            *(bf16x8*)(&lA[m][c ^ (m & 7)][0]) =
                *(const bf16x8*)(X + (size_t)(m0 + m) * HID + k0 + 8 * c);
        }
#pragma unroll
        for (int i = 0; i < 2; i++) {
            int uu = tid + 256 * i;
            int m = uu >> 3, c = uu & 7;
            *(bf16x8*)(&lB[m][c ^ (m & 7)][0]) =
                *(const bf16x8*)(Wb + (size_t)(n0 + m) * HID + k0 + 8 * c);
        }
        __syncthreads();
#pragma unroll
        for (int ks = 0; ks < 2; ks++) {
            bf16x8 af[2], bfr[2];
#pragma unroll
            for (int i = 0; i < 2; i++) {
                af[i]  = *(const bf16x8*)(&lA[wm + 16 * i + l16][(4 * ks + lc) ^ l7][0]);
                bfr[i] = *(const bf16x8*)(&lB[wn + 16 * i + l16][(4 * ks + lc) ^ l7][0]);
            }
#pragma unroll
            for (int i = 0; i < 2; i++)
#pragma unroll
                for (int j = 0; j < 2; j++)
                    acc[i][j] = __builtin_amdgcn_mfma_f32_16x16x32_bf16(
                        af[i], bfr[j], acc[i][j], 0, 0, 0);
        }
    }
#pragma unroll
    for (int i = 0; i < 2; i++) {
        int row = m0 + wm + 16 * i + 4 * lc;
#pragma unroll
        for (int j = 0; j < 2; j++) {
            int col = n0 + wn + 16 * j + l16;
#pragma unroll
            for (int r = 0; r < 4; r++)
                Y[(size_t)(row + r) * HID + col] = acc[i][j][r];
        }
    }
}

// ---------------- Causal attention: K direct from global, V in LDS --------------
// Ledger: R12 = 132.8 (best run; ~135 config mean). Noise band ~±3us — only
// >8us levers are resolvable. R13/R16 dbuf, R15 cvt-fold, R17 fused-combine
// (agent fences -> L2 writebacks, 355us), R18 XCD remap: all no-help.
// R19 (this round): per-CU LDS-pipe budget is the largest resource bill
// (~22us/CU: 20 ds ops x ~10cy x 260 wave-tiles). K's LDS roundtrip is
// algebraically removable: the staged+swizzled fragment each lane reads is
// exactly K[kt*64+16j+l16][32ks+8lc+0..7] — load it straight from global
// (L1-hot: 4 waves re-read the same 8KB tile; L2-resident: 2MB/4 heads/XCD).
// LDS ops 20 -> 10 per wave-tile; K traffic moves to the separate VMEM pipe.
// V stays in LDS (LDS BW 2x L1 — full-direct would regress).
__global__ __launch_bounds__(256) void attn_part(
    const bf16* __restrict__ Qh, const bf16* __restrict__ Kh,
    const bf16* __restrict__ Vt, float* __restrict__ Opart,
    float* __restrict__ Lpart)
{
    const int h = blockIdx.x >> 2;
    const int ch = blockIdx.x & 3;
    const int bt = 63 - (int)blockIdx.y;     // longest-first (LPT)
    const int qb = bt * 64;
    const int nkt = bt + 1;
    const int k0 = (nkt * ch) >> 2;
    const int k1 = (nkt * (ch + 1)) >> 2;
    const int tid = threadIdx.x;
    const int lane = tid & 63, w = tid >> 6;
    const int l16 = lane & 15, lc = lane >> 4, l7 = lane & 7;

    float* Op = Opart + ((size_t)(h * 64 + bt) * 4 + ch) * 4096;
    float* Lp = Lpart + ((size_t)(h * 64 + bt) * 4 + ch) * 64;

    if (k0 >= k1) {                          // empty chunk (small bt)
        const f32x4 z = {0.f, 0.f, 0.f, 0.f};
#pragma unroll
        for (int i = 0; i < 4; i++)
            *(f32x4*)(Op + 4 * (tid + 256 * i)) = z;
        if (tid < 64) Lp[tid] = 0.f;
        return;
    }

    __shared__ bf16 lV[64][8][8];            // 8 KiB (V only; K never staged)

    const bf16* Kb_ = Kh + (size_t)h * S_LEN * HD;
    const bf16* Vb_ = Vt + (size_t)h * HD * S_LEN;

    int srow[2], scol[2];
#pragma unroll
    for (int i = 0; i < 2; i++) {
        int uu = tid + 256 * i;
        srow[i] = uu >> 3;
        scol[i] = uu & 7;
    }

    bf16x8 qf[2];
    {
        const bf16* qrow = Qh + (size_t)h * S_LEN * HD + (size_t)(qb + 16 * w + l16) * HD;
        qf[0] = *(const bf16x8*)(qrow + 8 * lc);
        qf[1] = *(const bf16x8*)(qrow + 32 + 8 * lc);
    }
    // per-lane K fragment base: row (16j + l16), d-offset 8*lc
    const bf16* Kfb = Kb_ + (size_t)l16 * HD + 8 * lc;

    f32x4 oacc[4] = {};
    float l_sum = 0.f;

    // prologue: load V tile k0 into regs
    bf16x8 vr[2];
#pragma unroll
    for (int i = 0; i < 2; i++)
        vr[i] = *(const bf16x8*)(Vb_ + (size_t)srow[i] * S_LEN + k0 * 64 + 8 * scol[i]);

    for (int kt = k0; kt < k1; kt++) {
        // stage current V tile regs -> LDS
#pragma unroll
        for (int i = 0; i < 2; i++)
            *(bf16x8*)(&lV[srow[i]][scol[i] ^ (srow[i] & 7)][0]) = vr[i];
        __syncthreads();                     // staging visible to all waves

        // prefetch next V tile into regs (latency hidden behind compute)
        if (kt + 1 < k1) {
#pragma unroll
            for (int i = 0; i < 2; i++)
                vr[i] = *(const bf16x8*)(Vb_ + (size_t)srow[i] * S_LEN +
                                         (kt + 1) * 64 + 8 * scol[i]);
        }

        // S^T = K Q^T  — K fragments straight from global (L1/L2-hot)
        f32x4 sacc[4] = {};
        const bf16* Kt = Kfb + (size_t)kt * 64 * HD;
#pragma unroll
        for (int ks = 0; ks < 2; ks++) {
            bf16x8 kf[4];
#pragma unroll
            for (int j = 0; j < 4; j++)
                kf[j] = *(const bf16x8*)(Kt + (size_t)(16 * j) * HD + 32 * ks);
#pragma unroll
            for (int j = 0; j < 4; j++)
                sacc[j] = __builtin_amdgcn_mfma_f32_16x16x32_bf16(
                    kf[j], qf[ks], sacc[j], 0, 0, 0);
        }

        float pv[4][4];
#pragma unroll
        for (int j = 0; j < 4; j++)
#pragma unroll
            for (int r = 0; r < 4; r++)
                pv[j][r] = __builtin_amdgcn_exp2f(sacc[j][r] * SCALE_LOG2E);
        if (kt == nkt - 1) {                 // diagonal tile
            const int qg = qb + 16 * w + l16;
#pragma unroll
            for (int j = 0; j < 4; j++)
#pragma unroll
                for (int r = 0; r < 4; r++) {
                    const int keyg = kt * 64 + 16 * j + 4 * lc + r;
                    if (keyg > qg) pv[j][r] = 0.f;
                }
        }
#pragma unroll
        for (int j = 0; j < 4; j++)
            l_sum += (pv[j][0] + pv[j][1]) + (pv[j][2] + pv[j][3]);

        // P^T -> bf16 B-fragments fully in-register (no LDS roundtrip).
        unsigned wp[4][2];
#pragma unroll
        for (int j = 0; j < 4; j++) {
            asm("v_cvt_pk_bf16_f32 %0, %1, %2"
                : "=v"(wp[j][0]) : "v"(pv[j][0]), "v"(pv[j][1]));
            asm("v_cvt_pk_bf16_f32 %0, %1, %2"
                : "=v"(wp[j][1]) : "v"(pv[j][2]), "v"(pv[j][3]));
        }
        bf16x8 pb[2];
#pragma unroll
        for (int ks = 0; ks < 2; ks++) {
            uint4v ow;
#pragma unroll
            for (int u = 0; u < 2; u++) {
                unsigned a = wp[2 * ks][u], b = wp[2 * ks + 1][u];
                asm("v_permlane32_swap_b32 %0, %1" : "+v"(a), "+v"(b));
                asm("v_permlane16_swap_b32 %0, %1" : "+v"(a), "+v"(b));
                ow[u] = a;                   // word t = u   (keys 8lc+2u,   +1)
                ow[u + 2] = b;               // word t = u+2 (keys 8lc+2u+4, +1)
            }
            pb[ks] = __builtin_bit_cast(bf16x8, ow);
        }

        // O^T += V^T P^T
#pragma unroll
        for (int ks = 0; ks < 2; ks++)
#pragma unroll
            for (int j = 0; j < 4; j++) {
                bf16x8 vf = *(const bf16x8*)(&lV[16 * j + l16][(4 * ks + lc) ^ l7][0]);
                oacc[j] = __builtin_amdgcn_mfma_f32_16x16x32_bf16(
                    vf, pb[ks], oacc[j], 0, 0, 0);
            }

        __syncthreads();                     // V reads done; next iter may overwrite
    }

    // l: combine 4 lc-replicas of each q
    l_sum += __shfl_xor(l_sum, 16, 64);
    l_sum += __shfl_xor(l_sum, 32, 64);
    if (lane < 16) Lp[16 * w + l16] = l_sum;

    // unnormalized O^T partial: Op[q*64+d]
#pragma unroll
    for (int j = 0; j < 4; j++)
        *(f32x4*)(Op + (size_t)(16 * w + l16) * 64 + 16 * j + 4 * lc) = oacc[j];
}

// combine: O = (O0+O1+O2+O3)/(l0+l1+l2+l3) -> bf16 Ob[s][h*64+d]
__global__ __launch_bounds__(256) void attn_combine(
    const float* __restrict__ Opart, const float* __restrict__ Lpart,
    bf16* __restrict__ Ob)
{
    const int h = blockIdx.x, bt = blockIdx.y;
    const size_t base = (size_t)(h * 64 + bt) * 4;
    const float* O0 = Opart + base * 4096;
    const float* L0 = Lpart + base * 64;
    const int t = threadIdx.x;
    const int q = t >> 2, dq = (t & 3) * 16;
    const float l = (L0[q] + L0[64 + q]) + (L0[128 + q] + L0[192 + q]);
    const float inv = 1.0f / l;
    bf16* out = Ob + (size_t)(bt * 64 + q) * HID + h * HD + dq;
#pragma unroll
    for (int g = 0; g < 2; g++) {
        bf16x8 o8;
#pragma unroll
        for (int e = 0; e < 2; e++) {
            const int off = q * 64 + dq + 8 * g + 4 * e;
            f32x4 a = *(const f32x4*)(O0 + off);
            f32x4 b = *(const f32x4*)(O0 + 4096 + off);
            f32x4 c = *(const f32x4*)(O0 + 8192 + off);
            f32x4 d = *(const f32x4*)(O0 + 12288 + off);
#pragma unroll
            for (int r = 0; r < 4; r++)
                o8[4 * e + r] = (bf16)(((a[r] + b[r]) + (c[r] + d[r])) * inv);
        }
        *(bf16x8*)(out + 8 * g) = o8;
    }
}

// ---------------- launch ----------------
extern "C" void kernel_launch(void* const* d_in, const int* in_sizes, int n_in,
                              void* d_out, int out_size, void* d_ws, size_t ws_size,
                              hipStream_t stream) {
    const float* hs   = (const float*)d_in[0];
    const float* Wq   = (const float*)d_in[1];
    const float* Wk   = (const float*)d_in[2];
    const float* Wv   = (const float*)d_in[3];
    const float* Wo   = (const float*)d_in[4];
    const float* cosT = (const float*)d_in[5];
    const float* sinT = (const float*)d_in[6];
    const int*   nreg = (const int*)d_in[7];

    char* ws = (char*)d_ws;
    const size_t MiB = 1 << 20;
    bf16*  Qh    = (bf16*)(ws);                         // 0-4   [8][S][64]
    bf16*  Kh    = (bf16*)(ws + 4 * MiB);               // 4-8   [8][S][64]
    bf16*  Vt    = (bf16*)(ws + 8 * MiB);               // 8-12  [8][64][S]
    bf16*  Ob    = (bf16*)(ws + 12 * MiB);              // 12-16 [S][512]
    float* Opart = (float*)(ws + 16 * MiB);             // 16-48 (2048 x 16KB)
    float* Lpart = (float*)(ws + 48 * MiB);             // 48-48.5
    bf16*  Xb    = (bf16*)(ws + 49 * MiB);              // 49-53 hidden bf16
    bf16*  Wqb   = (bf16*)(ws + 53 * MiB);
    bf16*  Wkb   = (bf16*)(ws + 53 * MiB + 512 * 1024);
    bf16*  Wvb   = (bf16*)(ws + 54 * MiB);
    bf16*  Wob   = (bf16*)(ws + 54 * MiB + 512 * 1024);

    cvt_in<<<3072, 256, 0, stream>>>(hs, Wq, Wk, Wv, Wo, Xb, Wqb, Wkb, Wvb, Wob);
    gemm_qkv<<<dim3(4, 64, 3), 256, 0, stream>>>(Xb, Wqb, Wkb, Wvb,
                                                 cosT, sinT, nreg, Qh, Kh, Vt);
    attn_part<<<dim3(32, 64), 256, 0, stream>>>(Qh, Kh, Vt, Opart, Lpart);
    attn_combine<<<dim3(8, 64), 256, 0, stream>>>(Opart, Lpart, Ob);
    gemm_out<<<dim3(8, 64), 256, 0, stream>>>(Ob, Wob, (float*)d_out);
}

// Round 9
// 132.245 us; speedup vs baseline: 1.3589x; 1.3589x over previous
//
#include <hip/hip_runtime.h>
#include <cstdint>
#include <cstddef>

#define S_LEN 4096
#define HID   512
#define NHEAD 8
#define HD    64
// (1/sqrt(64)) * log2(e)
#define SCALE_LOG2E 0.1803368801111204f

typedef __bf16 bf16;
typedef __bf16 bf16x8 __attribute__((ext_vector_type(8)));
typedef __bf16 bf16x4 __attribute__((ext_vector_type(4)));
typedef float  f32x4  __attribute__((ext_vector_type(4)));
typedef unsigned uint4v __attribute__((ext_vector_type(4)));

// ---------------- fused input conversion: X + 4 weights -> bf16 ----------------
// R15: folding this into GEMM staging regressed (+6.6us). Keep the kernel.
__global__ __launch_bounds__(256) void cvt_in(
    const float* __restrict__ hs, const float* __restrict__ wq,
    const float* __restrict__ wk, const float* __restrict__ wv,
    const float* __restrict__ wo,
    bf16* __restrict__ xb, bf16* __restrict__ wqb, bf16* __restrict__ wkb,
    bf16* __restrict__ wvb, bf16* __restrict__ wob)
{
    int e = (blockIdx.x * 256 + threadIdx.x) * 4;
    const float* s; bf16* d; int o;
    if (e < 2 * 1024 * 1024) { s = hs; d = xb; o = e; }
    else {
        int t = e - 2 * 1024 * 1024;
        int wi = t >> 18;
        o = t & ((1 << 18) - 1);
        s = (wi == 0) ? wq : (wi == 1) ? wk : (wi == 2) ? wv : wo;
        d = (wi == 0) ? wqb : (wi == 1) ? wkb : (wi == 2) ? wvb : wob;
    }
    const float4 v = *(const float4*)(s + o);
    bf16x4 ob;
    ob[0] = (bf16)v.x; ob[1] = (bf16)v.y; ob[2] = (bf16)v.z; ob[3] = (bf16)v.w;
    *(bf16x4*)(d + o) = ob;
}

// ---------------- QKV GEMM, bf16 in, fused RoPE/transpose epilogue ----------------
__global__ __launch_bounds__(256) void gemm_qkv(
    const bf16* __restrict__ Xb,
    const bf16* __restrict__ W0, const bf16* __restrict__ W1, const bf16* __restrict__ W2,
    const float* __restrict__ cosT, const float* __restrict__ sinT,
    const int* __restrict__ nregp,
    bf16* __restrict__ Qh, bf16* __restrict__ Kh, bf16* __restrict__ Vt)
{
    const int z = blockIdx.z;
    const bf16* W = (z == 0) ? W0 : (z == 1 ? W1 : W2);
    const int m0 = blockIdx.y * 64, n0 = blockIdx.x * 128;
    __shared__ bf16 lA[64][8][8];
    __shared__ bf16 lB[128][8][8];
    __shared__ bf16 scratch[64][136];
    const int tid = threadIdx.x;
    const int lane = tid & 63, w = tid >> 6;
    const int l16 = lane & 15, lc = lane >> 4, l7 = lane & 7;
    const int wm = (w & 1) * 32, wn = (w >> 1) * 64;
    f32x4 acc[2][4] = {};

    for (int k0 = 0; k0 < HID; k0 += 64) {
        __syncthreads();
#pragma unroll
        for (int i = 0; i < 2; i++) {
            int uu = tid + 256 * i;
            int m = uu >> 3, c = uu & 7;
            *(bf16x8*)(&lA[m][c ^ (m & 7)][0]) =
                *(const bf16x8*)(Xb + (size_t)(m0 + m) * HID + k0 + 8 * c);
        }
#pragma unroll
        for (int i = 0; i < 4; i++) {
            int uu = tid + 256 * i;
            int m = uu >> 3, c = uu & 7;
            *(bf16x8*)(&lB[m][c ^ (m & 7)][0]) =
                *(const bf16x8*)(W + (size_t)(n0 + m) * HID + k0 + 8 * c);
        }
        __syncthreads();
#pragma unroll
        for (int ks = 0; ks < 2; ks++) {
            bf16x8 af[2], bfr[4];
#pragma unroll
            for (int i = 0; i < 2; i++)
                af[i]  = *(const bf16x8*)(&lA[wm + 16 * i + l16][(4 * ks + lc) ^ l7][0]);
#pragma unroll
            for (int j = 0; j < 4; j++)
                bfr[j] = *(const bf16x8*)(&lB[wn + 16 * j + l16][(4 * ks + lc) ^ l7][0]);
#pragma unroll
            for (int i = 0; i < 2; i++)
#pragma unroll
                for (int j = 0; j < 4; j++)
                    acc[i][j] = __builtin_amdgcn_mfma_f32_16x16x32_bf16(
                        af[i], bfr[j], acc[i][j], 0, 0, 0);
        }
    }

    if (z == 2) {
        const int h = (n0 + wn) >> 6;
#pragma unroll
        for (int i = 0; i < 2; i++) {
            const int s0r = m0 + wm + 16 * i + 4 * lc;
#pragma unroll
            for (int j = 0; j < 4; j++) {
                const int dl = 16 * j + l16;
                bf16x4 o;
#pragma unroll
                for (int r = 0; r < 4; r++) o[r] = (bf16)acc[i][j][r];
                *(bf16x4*)(Vt + ((size_t)(h * HD + dl)) * S_LEN + s0r) = o;
            }
        }
    } else {
        const int nreg = *nregp;
        bf16* dst = (z == 0) ? Qh : Kh;
#pragma unroll
        for (int i = 0; i < 2; i++) {
            const int sl0 = wm + 16 * i + 4 * lc;
#pragma unroll
            for (int r = 0; r < 4; r++) {
                const int s = m0 + sl0 + r;
                float c0 = 1.f, sn0 = 0.f, c1 = 1.f, sn1 = 0.f;
                if (s >= nreg) {
                    const int p = s - nreg;
                    c0  = cosT[(size_t)p * HD + l16];
                    sn0 = sinT[(size_t)p * HD + l16];
                    c1  = cosT[(size_t)p * HD + 16 + l16];
                    sn1 = sinT[(size_t)p * HD + 16 + l16];
                }
                const float x0 = acc[i][0][r], x1 = acc[i][1][r];
                const float x2 = acc[i][2][r], x3 = acc[i][3][r];
                bf16* row = &scratch[sl0 + r][wn];
                row[l16]      = (bf16)(x0 * c0 - x2 * sn0);
                row[l16 + 16] = (bf16)(x1 * c1 - x3 * sn1);
                row[l16 + 32] = (bf16)(x2 * c0 + x0 * sn0);
                row[l16 + 48] = (bf16)(x3 * c1 + x1 * sn1);
            }
        }
        __syncthreads();
        const int h0 = n0 >> 6;
#pragma unroll
        for (int i = 0; i < 4; i++) {
            int u = tid + 256 * i;
            int row = u >> 4, c = u & 15;
            bf16x8 val = *(const bf16x8*)(&scratch[row][c * 8]);
            *(bf16x8*)(dst + ((size_t)(h0 + (c >> 3)) * S_LEN + m0 + row) * HD +
                       (c & 7) * 8) = val;
        }
    }
}

// ---------------- output GEMM: bf16 A x bf16 W, fp32 out ----------
__global__ __launch_bounds__(256) void gemm_out(
    const bf16* __restrict__ X, const bf16* __restrict__ Wb,
    float* __restrict__ Y)
{
    const int m0 = blockIdx.y * 64, n0 = blockIdx.x * 64;
    __shared__ bf16 lA[64][8][8];
    __shared__ bf16 lB[64][8][8];
    const int tid = threadIdx.x;
    const int lane = tid & 63, w = tid >> 6;
    const int l16 = lane & 15, lc = lane >> 4, l7 = lane & 7;
    const int wm = (w & 1) * 32, wn = (w >> 1) * 32;
    f32x4 acc[2][2] = {};

    for (int k0 = 0; k0 < HID; k0 += 64) {
        __syncthreads();
#pragma unroll
        for (int i = 0; i < 2; i++) {
            int uu = tid + 256 * i;
            int m = uu >> 3, c = uu & 7;
            *(bf16x8*)(&lA[m][c ^ (m & 7)][0]) =
                *(const bf16x8*)(X + (size_t)(m0 + m) * HID + k0 + 8 * c);
        }
#pragma unroll
        for (int i = 0; i < 2; i++) {
            int uu = tid + 256 * i;
            int m = uu >> 3, c = uu & 7;
            *(bf16x8*)(&lB[m][c ^ (m & 7)][0]) =
                *(const bf16x8*)(Wb + (size_t)(n0 + m) * HID + k0 + 8 * c);
        }
        __syncthreads();
#pragma unroll
        for (int ks = 0; ks < 2; ks++) {
            bf16x8 af[2], bfr[2];
#pragma unroll
            for (int i = 0; i < 2; i++) {
                af[i]  = *(const bf16x8*)(&lA[wm + 16 * i + l16][(4 * ks + lc) ^ l7][0]);
                bfr[i] = *(const bf16x8*)(&lB[wn + 16 * i + l16][(4 * ks + lc) ^ l7][0]);
            }
#pragma unroll
            for (int i = 0; i < 2; i++)
#pragma unroll
                for (int j = 0; j < 2; j++)
                    acc[i][j] = __builtin_amdgcn_mfma_f32_16x16x32_bf16(
                        af[i], bfr[j], acc[i][j], 0, 0, 0);
        }
    }
#pragma unroll
    for (int i = 0; i < 2; i++) {
        int row = m0 + wm + 16 * i + 4 * lc;
#pragma unroll
        for (int j = 0; j < 2; j++) {
            int col = n0 + wn + 16 * j + l16;
#pragma unroll
            for (int r = 0; r < 4; r++)
                Y[(size_t)(row + r) * HID + col] = acc[i][j][r];
        }
    }
}

// ---------------- Causal attention: R12 loop verbatim, 2-way key split ----------
// Ledger: R12 = 132.8 (best). All loop restructures regressed:
//  R13/R16 dbuf (+3/+4), R17 fused-combine agent fences (+300),
//  R19 K-direct-from-global (+47: MFMA-layout gather = uncoalesced VMEM,
//  16 cache lines per fragment — LDS staging exists to coalesce exactly this).
// R19 counters: MfmaUtil 8%, VALUBusy 17%, Occ 36% -> latency-bound, pipes idle.
// R20 (this round): loop body untouched; only the CHUNK SPLIT 4 -> 2.
// Halves Opart/Lpart traffic (32MB+32MB -> 16+16), halves combine reads,
// doubles per-block work (better amortization), keeps >=4 blocks/CU
// (above r11's measured 2/CU regression point).
__global__ __launch_bounds__(256) void attn_part(
    const bf16* __restrict__ Qh, const bf16* __restrict__ Kh,
    const bf16* __restrict__ Vt, float* __restrict__ Opart,
    float* __restrict__ Lpart)
{
    const int h = blockIdx.x >> 1;
    const int ch = blockIdx.x & 1;
    const int bt = 63 - (int)blockIdx.y;     // longest-first (LPT)
    const int qb = bt * 64;
    const int nkt = bt + 1;
    const int k0 = (nkt * ch) >> 1;
    const int k1 = (nkt * (ch + 1)) >> 1;
    const int tid = threadIdx.x;
    const int lane = tid & 63, w = tid >> 6;
    const int l16 = lane & 15, lc = lane >> 4, l7 = lane & 7;

    float* Op = Opart + ((size_t)(h * 64 + bt) * 2 + ch) * 4096;
    float* Lp = Lpart + ((size_t)(h * 64 + bt) * 2 + ch) * 64;

    if (k0 >= k1) {                          // empty chunk (bt=0, ch=0 only)
        const f32x4 z = {0.f, 0.f, 0.f, 0.f};
#pragma unroll
        for (int i = 0; i < 4; i++)
            *(f32x4*)(Op + 4 * (tid + 256 * i)) = z;
        if (tid < 64) Lp[tid] = 0.f;
        return;
    }

    __shared__ bf16 lK[64][8][8];            // 8 KiB (single buffer)
    __shared__ bf16 lV[64][8][8];            // 8 KiB

    const bf16* Kb_ = Kh + (size_t)h * S_LEN * HD;
    const bf16* Vb_ = Vt + (size_t)h * HD * S_LEN;

    int srow[2], scol[2];
#pragma unroll
    for (int i = 0; i < 2; i++) {
        int uu = tid + 256 * i;
        srow[i] = uu >> 3;
        scol[i] = uu & 7;
    }

    bf16x8 qf[2];
    {
        const bf16* qrow = Qh + (size_t)h * S_LEN * HD + (size_t)(qb + 16 * w + l16) * HD;
        qf[0] = *(const bf16x8*)(qrow + 8 * lc);
        qf[1] = *(const bf16x8*)(qrow + 32 + 8 * lc);
    }
    f32x4 oacc[4] = {};
    float l_sum = 0.f;

    // prologue: load tile k0 into regs
    bf16x8 kr[2], vr[2];
#pragma unroll
    for (int i = 0; i < 2; i++) {
        kr[i] = *(const bf16x8*)(Kb_ + (size_t)(k0 * 64 + srow[i]) * HD + 8 * scol[i]);
        vr[i] = *(const bf16x8*)(Vb_ + (size_t)srow[i] * S_LEN + k0 * 64 + 8 * scol[i]);
    }

    for (int kt = k0; kt < k1; kt++) {
        // stage current tile regs -> LDS
#pragma unroll
        for (int i = 0; i < 2; i++) {
            *(bf16x8*)(&lK[srow[i]][scol[i] ^ (srow[i] & 7)][0]) = kr[i];
            *(bf16x8*)(&lV[srow[i]][scol[i] ^ (srow[i] & 7)][0]) = vr[i];
        }
        __syncthreads();                     // staging visible to all waves

        // prefetch next tile into regs (latency hidden behind compute)
        if (kt + 1 < k1) {
#pragma unroll
            for (int i = 0; i < 2; i++) {
                kr[i] = *(const bf16x8*)(Kb_ + (size_t)((kt + 1) * 64 + srow[i]) * HD +
                                         8 * scol[i]);
                vr[i] = *(const bf16x8*)(Vb_ + (size_t)srow[i] * S_LEN +
                                         (kt + 1) * 64 + 8 * scol[i]);
            }
        }

        // S^T = K Q^T
        f32x4 sacc[4] = {};
#pragma unroll
        for (int ks = 0; ks < 2; ks++)
#pragma unroll
            for (int j = 0; j < 4; j++) {
                bf16x8 kf = *(const bf16x8*)(&lK[16 * j + l16][(4 * ks + lc) ^ l7][0]);
                sacc[j] = __builtin_amdgcn_mfma_f32_16x16x32_bf16(
                    kf, qf[ks], sacc[j], 0, 0, 0);
            }

        float pv[4][4];
#pragma unroll
        for (int j = 0; j < 4; j++)
#pragma unroll
            for (int r = 0; r < 4; r++)
                pv[j][r] = __builtin_amdgcn_exp2f(sacc[j][r] * SCALE_LOG2E);
        if (kt == nkt - 1) {                 // diagonal tile
            const int qg = qb + 16 * w + l16;
#pragma unroll
            for (int j = 0; j < 4; j++)
#pragma unroll
                for (int r = 0; r < 4; r++) {
                    const int keyg = kt * 64 + 16 * j + 4 * lc + r;
                    if (keyg > qg) pv[j][r] = 0.f;
                }
        }
#pragma unroll
        for (int j = 0; j < 4; j++)
            l_sum += (pv[j][0] + pv[j][1]) + (pv[j][2] + pv[j][3]);

        // P^T -> bf16 B-fragments fully in-register (no LDS roundtrip).
        unsigned wp[4][2];
#pragma unroll
        for (int j = 0; j < 4; j++) {
            asm("v_cvt_pk_bf16_f32 %0, %1, %2"
                : "=v"(wp[j][0]) : "v"(pv[j][0]), "v"(pv[j][1]));
            asm("v_cvt_pk_bf16_f32 %0, %1, %2"
                : "=v"(wp[j][1]) : "v"(pv[j][2]), "v"(pv[j][3]));
        }
        bf16x8 pb[2];
#pragma unroll
        for (int ks = 0; ks < 2; ks++) {
            uint4v ow;
#pragma unroll
            for (int u = 0; u < 2; u++) {
                unsigned a = wp[2 * ks][u], b = wp[2 * ks + 1][u];
                asm("v_permlane32_swap_b32 %0, %1" : "+v"(a), "+v"(b));
                asm("v_permlane16_swap_b32 %0, %1" : "+v"(a), "+v"(b));
                ow[u] = a;                   // word t = u   (keys 8lc+2u,   +1)
                ow[u + 2] = b;               // word t = u+2 (keys 8lc+2u+4, +1)
            }
            pb[ks] = __builtin_bit_cast(bf16x8, ow);
        }

        // O^T += V^T P^T
#pragma unroll
        for (int ks = 0; ks < 2; ks++)
#pragma unroll
            for (int j = 0; j < 4; j++) {
                bf16x8 vf = *(const bf16x8*)(&lV[16 * j + l16][(4 * ks + lc) ^ l7][0]);
                oacc[j] = __builtin_amdgcn_mfma_f32_16x16x32_bf16(
                    vf, pb[ks], oacc[j], 0, 0, 0);
            }

        __syncthreads();                     // K/V reads done; next iter may overwrite
    }

    // l: combine 4 lc-replicas of each q
    l_sum += __shfl_xor(l_sum, 16, 64);
    l_sum += __shfl_xor(l_sum, 32, 64);
    if (lane < 16) Lp[16 * w + l16] = l_sum;

    // unnormalized O^T partial: Op[q*64+d]
#pragma unroll
    for (int j = 0; j < 4; j++)
        *(f32x4*)(Op + (size_t)(16 * w + l16) * 64 + 16 * j + 4 * lc) = oacc[j];
}

// combine: O = (O0+O1)/(l0+l1) -> bf16 Ob[s][h*64+d]  (2-way split)
__global__ __launch_bounds__(256) void attn_combine(
    const float* __restrict__ Opart, const float* __restrict__ Lpart,
    bf16* __restrict__ Ob)
{
    const int h = blockIdx.x, bt = blockIdx.y;
    const size_t base = (size_t)(h * 64 + bt) * 2;
    const float* O0 = Opart + base * 4096;
    const float* L0 = Lpart + base * 64;
    const int t = threadIdx.x;
    const int q = t >> 2, dq = (t & 3) * 16;
    const float l = L0[q] + L0[64 + q];
    const float inv = 1.0f / l;
    bf16* out = Ob + (size_t)(bt * 64 + q) * HID + h * HD + dq;
#pragma unroll
    for (int g = 0; g < 2; g++) {
        bf16x8 o8;
#pragma unroll
        for (int e = 0; e < 2; e++) {
            const int off = q * 64 + dq + 8 * g + 4 * e;
            f32x4 a = *(const f32x4*)(O0 + off);
            f32x4 b = *(const f32x4*)(O0 + 4096 + off);
#pragma unroll
            for (int r = 0; r < 4; r++)
                o8[4 * e + r] = (bf16)((a[r] + b[r]) * inv);
        }
        *(bf16x8*)(out + 8 * g) = o8;
    }
}

// ---------------- launch ----------------
extern "C" void kernel_launch(void* const* d_in, const int* in_sizes, int n_in,
                              void* d_out, int out_size, void* d_ws, size_t ws_size,
                              hipStream_t stream) {
    const float* hs   = (const float*)d_in[0];
    const float* Wq   = (const float*)d_in[1];
    const float* Wk   = (const float*)d_in[2];
    const float* Wv   = (const float*)d_in[3];
    const float* Wo   = (const float*)d_in[4];
    const float* cosT = (const float*)d_in[5];
    const float* sinT = (const float*)d_in[6];
    const int*   nreg = (const int*)d_in[7];

    char* ws = (char*)d_ws;
    const size_t MiB = 1 << 20;
    bf16*  Qh    = (bf16*)(ws);                         // 0-4   [8][S][64]
    bf16*  Kh    = (bf16*)(ws + 4 * MiB);               // 4-8   [8][S][64]
    bf16*  Vt    = (bf16*)(ws + 8 * MiB);               // 8-12  [8][64][S]
    bf16*  Ob    = (bf16*)(ws + 12 * MiB);              // 12-16 [S][512]
    float* Opart = (float*)(ws + 16 * MiB);             // 16-32 (1024 x 16KB)
    float* Lpart = (float*)(ws + 48 * MiB);             // 48-48.25
    bf16*  Xb    = (bf16*)(ws + 49 * MiB);              // 49-53 hidden bf16
    bf16*  Wqb   = (bf16*)(ws + 53 * MiB);
    bf16*  Wkb   = (bf16*)(ws + 53 * MiB + 512 * 1024);
    bf16*  Wvb   = (bf16*)(ws + 54 * MiB);
    bf16*  Wob   = (bf16*)(ws + 54 * MiB + 512 * 1024);

    cvt_in<<<3072, 256, 0, stream>>>(hs, Wq, Wk, Wv, Wo, Xb, Wqb, Wkb, Wvb, Wob);
    gemm_qkv<<<dim3(4, 64, 3), 256, 0, stream>>>(Xb, Wqb, Wkb, Wvb,
                                                 cosT, sinT, nreg, Qh, Kh, Vt);
    attn_part<<<dim3(16, 64), 256, 0, stream>>>(Qh, Kh, Vt, Opart, Lpart);
    attn_combine<<<dim3(8, 64), 256, 0, stream>>>(Opart, Lpart, Ob);
    gemm_out<<<dim3(8, 64), 256, 0, stream>>>(Ob, Wob, (float*)d_out);
}

// Round 10
// 131.519 us; speedup vs baseline: 1.3664x; 1.0055x over previous
//
#include <hip/hip_runtime.h>
#include <cstdint>
#include <cstddef>

#define S_LEN 4096
#define HID   512
#define NHEAD 8
#define HD    64
// (1/sqrt(64)) * log2(e)
#define SCALE_LOG2E 0.1803368801111204f

typedef __bf16 bf16;
typedef __bf16 bf16x8 __attribute__((ext_vector_type(8)));
typedef __bf16 bf16x4 __attribute__((ext_vector_type(4)));
typedef float  f32x4  __attribute__((ext_vector_type(4)));
typedef unsigned uint4v __attribute__((ext_vector_type(4)));

// ---------------- fused input conversion: X + 4 weights -> bf16 ----------------
// R15: folding this into GEMM staging regressed (+6.6us). Keep the kernel.
__global__ __launch_bounds__(256) void cvt_in(
    const float* __restrict__ hs, const float* __restrict__ wq,
    const float* __restrict__ wk, const float* __restrict__ wv,
    const float* __restrict__ wo,
    bf16* __restrict__ xb, bf16* __restrict__ wqb, bf16* __restrict__ wkb,
    bf16* __restrict__ wvb, bf16* __restrict__ wob)
{
    int e = (blockIdx.x * 256 + threadIdx.x) * 4;
    const float* s; bf16* d; int o;
    if (e < 2 * 1024 * 1024) { s = hs; d = xb; o = e; }
    else {
        int t = e - 2 * 1024 * 1024;
        int wi = t >> 18;
        o = t & ((1 << 18) - 1);
        s = (wi == 0) ? wq : (wi == 1) ? wk : (wi == 2) ? wv : wo;
        d = (wi == 0) ? wqb : (wi == 1) ? wkb : (wi == 2) ? wvb : wob;
    }
    const float4 v = *(const float4*)(s + o);
    bf16x4 ob;
    ob[0] = (bf16)v.x; ob[1] = (bf16)v.y; ob[2] = (bf16)v.z; ob[3] = (bf16)v.w;
    *(bf16x4*)(d + o) = ob;
}

// ---------------- QKV GEMM, bf16 in, fused RoPE/transpose epilogue ----------------
// R21 (this round): register-prefetch software pipeline, ported from the attn
// R12 loop. Old k-loop had global-load latency serially ON the critical path
// every K-step (load issued after barrier, consumed immediately). Now tile k+1
// is loaded into regs right after the staging barrier, hiding its latency
// under the MFMA phase. Same barriers, same bytes, same staging indices.
__global__ __launch_bounds__(256) void gemm_qkv(
    const bf16* __restrict__ Xb,
    const bf16* __restrict__ W0, const bf16* __restrict__ W1, const bf16* __restrict__ W2,
    const float* __restrict__ cosT, const float* __restrict__ sinT,
    const int* __restrict__ nregp,
    bf16* __restrict__ Qh, bf16* __restrict__ Kh, bf16* __restrict__ Vt)
{
    const int z = blockIdx.z;
    const bf16* W = (z == 0) ? W0 : (z == 1 ? W1 : W2);
    const int m0 = blockIdx.y * 64, n0 = blockIdx.x * 128;
    __shared__ bf16 lA[64][8][8];
    __shared__ bf16 lB[128][8][8];
    __shared__ bf16 scratch[64][136];
    const int tid = threadIdx.x;
    const int lane = tid & 63, w = tid >> 6;
    const int l16 = lane & 15, lc = lane >> 4, l7 = lane & 7;
    const int wm = (w & 1) * 32, wn = (w >> 1) * 64;
    f32x4 acc[2][4] = {};

    int am[2], ac[2], bm[4], bc[4];
#pragma unroll
    for (int i = 0; i < 2; i++) {
        int uu = tid + 256 * i;
        am[i] = uu >> 3; ac[i] = uu & 7;
    }
#pragma unroll
    for (int i = 0; i < 4; i++) {
        int uu = tid + 256 * i;
        bm[i] = uu >> 3; bc[i] = uu & 7;
    }

    // prologue: load k=0 tiles into regs
    bf16x8 ar[2], br[4];
#pragma unroll
    for (int i = 0; i < 2; i++)
        ar[i] = *(const bf16x8*)(Xb + (size_t)(m0 + am[i]) * HID + 8 * ac[i]);
#pragma unroll
    for (int i = 0; i < 4; i++)
        br[i] = *(const bf16x8*)(W + (size_t)(n0 + bm[i]) * HID + 8 * bc[i]);

    for (int k0 = 0; k0 < HID; k0 += 64) {
        // stage current tile regs -> LDS
#pragma unroll
        for (int i = 0; i < 2; i++)
            *(bf16x8*)(&lA[am[i]][ac[i] ^ (am[i] & 7)][0]) = ar[i];
#pragma unroll
        for (int i = 0; i < 4; i++)
            *(bf16x8*)(&lB[bm[i]][bc[i] ^ (bm[i] & 7)][0]) = br[i];
        __syncthreads();                     // staging visible to all waves

        // prefetch next K-tile into regs (latency hidden behind MFMA)
        if (k0 + 64 < HID) {
#pragma unroll
            for (int i = 0; i < 2; i++)
                ar[i] = *(const bf16x8*)(Xb + (size_t)(m0 + am[i]) * HID +
                                         (k0 + 64) + 8 * ac[i]);
#pragma unroll
            for (int i = 0; i < 4; i++)
                br[i] = *(const bf16x8*)(W + (size_t)(n0 + bm[i]) * HID +
                                         (k0 + 64) + 8 * bc[i]);
        }

#pragma unroll
        for (int ks = 0; ks < 2; ks++) {
            bf16x8 af[2], bfr[4];
#pragma unroll
            for (int i = 0; i < 2; i++)
                af[i]  = *(const bf16x8*)(&lA[wm + 16 * i + l16][(4 * ks + lc) ^ l7][0]);
#pragma unroll
            for (int j = 0; j < 4; j++)
                bfr[j] = *(const bf16x8*)(&lB[wn + 16 * j + l16][(4 * ks + lc) ^ l7][0]);
#pragma unroll
            for (int i = 0; i < 2; i++)
#pragma unroll
                for (int j = 0; j < 4; j++)
                    acc[i][j] = __builtin_amdgcn_mfma_f32_16x16x32_bf16(
                        af[i], bfr[j], acc[i][j], 0, 0, 0);
        }
        __syncthreads();                     // LDS reads done; next iter restages
    }

    if (z == 2) {
        const int h = (n0 + wn) >> 6;
#pragma unroll
        for (int i = 0; i < 2; i++) {
            const int s0r = m0 + wm + 16 * i + 4 * lc;
#pragma unroll
            for (int j = 0; j < 4; j++) {
                const int dl = 16 * j + l16;
                bf16x4 o;
#pragma unroll
                for (int r = 0; r < 4; r++) o[r] = (bf16)acc[i][j][r];
                *(bf16x4*)(Vt + ((size_t)(h * HD + dl)) * S_LEN + s0r) = o;
            }
        }
    } else {
        const int nreg = *nregp;
        bf16* dst = (z == 0) ? Qh : Kh;
#pragma unroll
        for (int i = 0; i < 2; i++) {
            const int sl0 = wm + 16 * i + 4 * lc;
#pragma unroll
            for (int r = 0; r < 4; r++) {
                const int s = m0 + sl0 + r;
                float c0 = 1.f, sn0 = 0.f, c1 = 1.f, sn1 = 0.f;
                if (s >= nreg) {
                    const int p = s - nreg;
                    c0  = cosT[(size_t)p * HD + l16];
                    sn0 = sinT[(size_t)p * HD + l16];
                    c1  = cosT[(size_t)p * HD + 16 + l16];
                    sn1 = sinT[(size_t)p * HD + 16 + l16];
                }
                const float x0 = acc[i][0][r], x1 = acc[i][1][r];
                const float x2 = acc[i][2][r], x3 = acc[i][3][r];
                bf16* row = &scratch[sl0 + r][wn];
                row[l16]      = (bf16)(x0 * c0 - x2 * sn0);
                row[l16 + 16] = (bf16)(x1 * c1 - x3 * sn1);
                row[l16 + 32] = (bf16)(x2 * c0 + x0 * sn0);
                row[l16 + 48] = (bf16)(x3 * c1 + x1 * sn1);
            }
        }
        __syncthreads();
        const int h0 = n0 >> 6;
#pragma unroll
        for (int i = 0; i < 4; i++) {
            int u = tid + 256 * i;
            int row = u >> 4, c = u & 15;
            bf16x8 val = *(const bf16x8*)(&scratch[row][c * 8]);
            *(bf16x8*)(dst + ((size_t)(h0 + (c >> 3)) * S_LEN + m0 + row) * HD +
                       (c & 7) * 8) = val;
        }
    }
}

// ---------------- output GEMM: bf16 A x bf16 W, fp32 out ----------
// R21: same register-prefetch pipeline as gemm_qkv.
__global__ __launch_bounds__(256) void gemm_out(
    const bf16* __restrict__ X, const bf16* __restrict__ Wb,
    float* __restrict__ Y)
{
    const int m0 = blockIdx.y * 64, n0 = blockIdx.x * 64;
    __shared__ bf16 lA[64][8][8];
    __shared__ bf16 lB[64][8][8];
    const int tid = threadIdx.x;
    const int lane = tid & 63, w = tid >> 6;
    const int l16 = lane & 15, lc = lane >> 4, l7 = lane & 7;
    const int wm = (w & 1) * 32, wn = (w >> 1) * 32;
    f32x4 acc[2][2] = {};

    int am[2], ac[2];
#pragma unroll
    for (int i = 0; i < 2; i++) {
        int uu = tid + 256 * i;
        am[i] = uu >> 3; ac[i] = uu & 7;
    }

    bf16x8 ar[2], br[2];
#pragma unroll
    for (int i = 0; i < 2; i++) {
        ar[i] = *(const bf16x8*)(X  + (size_t)(m0 + am[i]) * HID + 8 * ac[i]);
        br[i] = *(const bf16x8*)(Wb + (size_t)(n0 + am[i]) * HID + 8 * ac[i]);
    }

    for (int k0 = 0; k0 < HID; k0 += 64) {
#pragma unroll
        for (int i = 0; i < 2; i++) {
            *(bf16x8*)(&lA[am[i]][ac[i] ^ (am[i] & 7)][0]) = ar[i];
            *(bf16x8*)(&lB[am[i]][ac[i] ^ (am[i] & 7)][0]) = br[i];
        }
        __syncthreads();

        if (k0 + 64 < HID) {
#pragma unroll
            for (int i = 0; i < 2; i++) {
                ar[i] = *(const bf16x8*)(X  + (size_t)(m0 + am[i]) * HID +
                                         (k0 + 64) + 8 * ac[i]);
                br[i] = *(const bf16x8*)(Wb + (size_t)(n0 + am[i]) * HID +
                                         (k0 + 64) + 8 * ac[i]);
            }
        }

#pragma unroll
        for (int ks = 0; ks < 2; ks++) {
            bf16x8 af[2], bfr[2];
#pragma unroll
            for (int i = 0; i < 2; i++) {
                af[i]  = *(const bf16x8*)(&lA[wm + 16 * i + l16][(4 * ks + lc) ^ l7][0]);
                bfr[i] = *(const bf16x8*)(&lB[wn + 16 * i + l16][(4 * ks + lc) ^ l7][0]);
            }
#pragma unroll
            for (int i = 0; i < 2; i++)
#pragma unroll
                for (int j = 0; j < 2; j++)
                    acc[i][j] = __builtin_amdgcn_mfma_f32_16x16x32_bf16(
                        af[i], bfr[j], acc[i][j], 0, 0, 0);
        }
        __syncthreads();
    }
#pragma unroll
    for (int i = 0; i < 2; i++) {
        int row = m0 + wm + 16 * i + 4 * lc;
#pragma unroll
        for (int j = 0; j < 2; j++) {
            int col = n0 + wn + 16 * j + l16;
#pragma unroll
            for (int r = 0; r < 4; r++)
                Y[(size_t)(row + r) * HID + col] = acc[i][j][r];
        }
    }
}

// ---------------- Causal attention: R12 loop verbatim, 2-way key split ----------
// Ledger: R12 = 132.8, R20 (2-way split) = 132.2 (tie; kept — less traffic).
// Attn is CLOSED: 6 experiments, 1 win (R12 in-reg P exchange), 5 null/regress
// (dbuf x2, fused-combine fences, K-direct-global, XCD remap, split width).
// Latency-bound at Occ 36%, MfmaUtil 8%, VALUBusy 17% — pipes idle.
__global__ __launch_bounds__(256) void attn_part(
    const bf16* __restrict__ Qh, const bf16* __restrict__ Kh,
    const bf16* __restrict__ Vt, float* __restrict__ Opart,
    float* __restrict__ Lpart)
{
    const int h = blockIdx.x >> 1;
    const int ch = blockIdx.x & 1;
    const int bt = 63 - (int)blockIdx.y;     // longest-first (LPT)
    const int qb = bt * 64;
    const int nkt = bt + 1;
    const int k0 = (nkt * ch) >> 1;
    const int k1 = (nkt * (ch + 1)) >> 1;
    const int tid = threadIdx.x;
    const int lane = tid & 63, w = tid >> 6;
    const int l16 = lane & 15, lc = lane >> 4, l7 = lane & 7;

    float* Op = Opart + ((size_t)(h * 64 + bt) * 2 + ch) * 4096;
    float* Lp = Lpart + ((size_t)(h * 64 + bt) * 2 + ch) * 64;

    if (k0 >= k1) {                          // empty chunk (bt=0, ch=0 only)
        const f32x4 z = {0.f, 0.f, 0.f, 0.f};
#pragma unroll
        for (int i = 0; i < 4; i++)
            *(f32x4*)(Op + 4 * (tid + 256 * i)) = z;
        if (tid < 64) Lp[tid] = 0.f;
        return;
    }

    __shared__ bf16 lK[64][8][8];            // 8 KiB (single buffer)
    __shared__ bf16 lV[64][8][8];            // 8 KiB

    const bf16* Kb_ = Kh + (size_t)h * S_LEN * HD;
    const bf16* Vb_ = Vt + (size_t)h * HD * S_LEN;

    int srow[2], scol[2];
#pragma unroll
    for (int i = 0; i < 2; i++) {
        int uu = tid + 256 * i;
        srow[i] = uu >> 3;
        scol[i] = uu & 7;
    }

    bf16x8 qf[2];
    {
        const bf16* qrow = Qh + (size_t)h * S_LEN * HD + (size_t)(qb + 16 * w + l16) * HD;
        qf[0] = *(const bf16x8*)(qrow + 8 * lc);
        qf[1] = *(const bf16x8*)(qrow + 32 + 8 * lc);
    }
    f32x4 oacc[4] = {};
    float l_sum = 0.f;

    // prologue: load tile k0 into regs
    bf16x8 kr[2], vr[2];
#pragma unroll
    for (int i = 0; i < 2; i++) {
        kr[i] = *(const bf16x8*)(Kb_ + (size_t)(k0 * 64 + srow[i]) * HD + 8 * scol[i]);
        vr[i] = *(const bf16x8*)(Vb_ + (size_t)srow[i] * S_LEN + k0 * 64 + 8 * scol[i]);
    }

    for (int kt = k0; kt < k1; kt++) {
        // stage current tile regs -> LDS
#pragma unroll
        for (int i = 0; i < 2; i++) {
            *(bf16x8*)(&lK[srow[i]][scol[i] ^ (srow[i] & 7)][0]) = kr[i];
            *(bf16x8*)(&lV[srow[i]][scol[i] ^ (srow[i] & 7)][0]) = vr[i];
        }
        __syncthreads();                     // staging visible to all waves

        // prefetch next tile into regs (latency hidden behind compute)
        if (kt + 1 < k1) {
#pragma unroll
            for (int i = 0; i < 2; i++) {
                kr[i] = *(const bf16x8*)(Kb_ + (size_t)((kt + 1) * 64 + srow[i]) * HD +
                                         8 * scol[i]);
                vr[i] = *(const bf16x8*)(Vb_ + (size_t)srow[i] * S_LEN +
                                         (kt + 1) * 64 + 8 * scol[i]);
            }
        }

        // S^T = K Q^T
        f32x4 sacc[4] = {};
#pragma unroll
        for (int ks = 0; ks < 2; ks++)
#pragma unroll
            for (int j = 0; j < 4; j++) {
                bf16x8 kf = *(const bf16x8*)(&lK[16 * j + l16][(4 * ks + lc) ^ l7][0]);
                sacc[j] = __builtin_amdgcn_mfma_f32_16x16x32_bf16(
                    kf, qf[ks], sacc[j], 0, 0, 0);
            }

        float pv[4][4];
#pragma unroll
        for (int j = 0; j < 4; j++)
#pragma unroll
            for (int r = 0; r < 4; r++)
                pv[j][r] = __builtin_amdgcn_exp2f(sacc[j][r] * SCALE_LOG2E);
        if (kt == nkt - 1) {                 // diagonal tile
            const int qg = qb + 16 * w + l16;
#pragma unroll
            for (int j = 0; j < 4; j++)
#pragma unroll
                for (int r = 0; r < 4; r++) {
                    const int keyg = kt * 64 + 16 * j + 4 * lc + r;
                    if (keyg > qg) pv[j][r] = 0.f;
                }
        }
#pragma unroll
        for (int j = 0; j < 4; j++)
            l_sum += (pv[j][0] + pv[j][1]) + (pv[j][2] + pv[j][3]);

        // P^T -> bf16 B-fragments fully in-register (no LDS roundtrip).
        unsigned wp[4][2];
#pragma unroll
        for (int j = 0; j < 4; j++) {
            asm("v_cvt_pk_bf16_f32 %0, %1, %2"
                : "=v"(wp[j][0]) : "v"(pv[j][0]), "v"(pv[j][1]));
            asm("v_cvt_pk_bf16_f32 %0, %1, %2"
                : "=v"(wp[j][1]) : "v"(pv[j][2]), "v"(pv[j][3]));
        }
        bf16x8 pb[2];
#pragma unroll
        for (int ks = 0; ks < 2; ks++) {
            uint4v ow;
#pragma unroll
            for (int u = 0; u < 2; u++) {
                unsigned a = wp[2 * ks][u], b = wp[2 * ks + 1][u];
                asm("v_permlane32_swap_b32 %0, %1" : "+v"(a), "+v"(b));
                asm("v_permlane16_swap_b32 %0, %1" : "+v"(a), "+v"(b));
                ow[u] = a;                   // word t = u   (keys 8lc+2u,   +1)
                ow[u + 2] = b;               // word t = u+2 (keys 8lc+2u+4, +1)
            }
            pb[ks] = __builtin_bit_cast(bf16x8, ow);
        }

        // O^T += V^T P^T
#pragma unroll
        for (int ks = 0; ks < 2; ks++)
#pragma unroll
            for (int j = 0; j < 4; j++) {
                bf16x8 vf = *(const bf16x8*)(&lV[16 * j + l16][(4 * ks + lc) ^ l7][0]);
                oacc[j] = __builtin_amdgcn_mfma_f32_16x16x32_bf16(
                    vf, pb[ks], oacc[j], 0, 0, 0);
            }

        __syncthreads();                     // K/V reads done; next iter may overwrite
    }

    // l: combine 4 lc-replicas of each q
    l_sum += __shfl_xor(l_sum, 16, 64);
    l_sum += __shfl_xor(l_sum, 32, 64);
    if (lane < 16) Lp[16 * w + l16] = l_sum;

    // unnormalized O^T partial: Op[q*64+d]
#pragma unroll
    for (int j = 0; j < 4; j++)
        *(f32x4*)(Op + (size_t)(16 * w + l16) * 64 + 16 * j + 4 * lc) = oacc[j];
}

// combine: O = (O0+O1)/(l0+l1) -> bf16 Ob[s][h*64+d]  (2-way split)
__global__ __launch_bounds__(256) void attn_combine(
    const float* __restrict__ Opart, const float* __restrict__ Lpart,
    bf16* __restrict__ Ob)
{
    const int h = blockIdx.x, bt = blockIdx.y;
    const size_t base = (size_t)(h * 64 + bt) * 2;
    const float* O0 = Opart + base * 4096;
    const float* L0 = Lpart + base * 64;
    const int t = threadIdx.x;
    const int q = t >> 2, dq = (t & 3) * 16;
    const float l = L0[q] + L0[64 + q];
    const float inv = 1.0f / l;
    bf16* out = Ob + (size_t)(bt * 64 + q) * HID + h * HD + dq;
#pragma unroll
    for (int g = 0; g < 2; g++) {
        bf16x8 o8;
#pragma unroll
        for (int e = 0; e < 2; e++) {
            const int off = q * 64 + dq + 8 * g + 4 * e;
            f32x4 a = *(const f32x4*)(O0 + off);
            f32x4 b = *(const f32x4*)(O0 + 4096 + off);
#pragma unroll
            for (int r = 0; r < 4; r++)
                o8[4 * e + r] = (bf16)((a[r] + b[r]) * inv);
        }
        *(bf16x8*)(out + 8 * g) = o8;
    }
}

// ---------------- launch ----------------
extern "C" void kernel_launch(void* const* d_in, const int* in_sizes, int n_in,
                              void* d_out, int out_size, void* d_ws, size_t ws_size,
                              hipStream_t stream) {
    const float* hs   = (const float*)d_in[0];
    const float* Wq   = (const float*)d_in[1];
    const float* Wk   = (const float*)d_in[2];
    const float* Wv   = (const float*)d_in[3];
    const float* Wo   = (const float*)d_in[4];
    const float* cosT = (const float*)d_in[5];
    const float* sinT = (const float*)d_in[6];
    const int*   nreg = (const int*)d_in[7];

    char* ws = (char*)d_ws;
    const size_t MiB = 1 << 20;
    bf16*  Qh    = (bf16*)(ws);                         // 0-4   [8][S][64]
    bf16*  Kh    = (bf16*)(ws + 4 * MiB);               // 4-8   [8][S][64]
    bf16*  Vt    = (bf16*)(ws + 8 * MiB);               // 8-12  [8][64][S]
    bf16*  Ob    = (bf16*)(ws + 12 * MiB);              // 12-16 [S][512]
    float* Opart = (float*)(ws + 16 * MiB);             // 16-32 (1024 x 16KB)
    float* Lpart = (float*)(ws + 48 * MiB);             // 48-48.25
    bf16*  Xb    = (bf16*)(ws + 49 * MiB);              // 49-53 hidden bf16
    bf16*  Wqb   = (bf16*)(ws + 53 * MiB);
    bf16*  Wkb   = (bf16*)(ws + 53 * MiB + 512 * 1024);
    bf16*  Wvb   = (bf16*)(ws + 54 * MiB);
    bf16*  Wob   = (bf16*)(ws + 54 * MiB + 512 * 1024);

    cvt_in<<<3072, 256, 0, stream>>>(hs, Wq, Wk, Wv, Wo, Xb, Wqb, Wkb, Wvb, Wob);
    gemm_qkv<<<dim3(4, 64, 3), 256, 0, stream>>>(Xb, Wqb, Wkb, Wvb,
                                                 cosT, sinT, nreg, Qh, Kh, Vt);
    attn_part<<<dim3(16, 64), 256, 0, stream>>>(Qh, Kh, Vt, Opart, Lpart);
    attn_combine<<<dim3(8, 64), 256, 0, stream>>>(Opart, Lpart, Ob);
    gemm_out<<<dim3(8, 64), 256, 0, stream>>>(Ob, Wob, (float*)d_out);
}